// Round 17
// baseline (95.642 us; speedup 1.0000x reference)
//
#include <hip/hip_runtime.h>

#define TSEQ 2048
#define NHEAD 16
#define HD 64
#define CDIM 1024
#define BT 4096  // B*T

typedef unsigned short u16;
typedef __bf16 bf16x8 __attribute__((ext_vector_type(8)));
typedef float f32x4 __attribute__((ext_vector_type(4)));
typedef float f32x16 __attribute__((ext_vector_type(16)));

union Frag {
  int4 i4;
  bf16x8 b;
  u16 u[8];
};

__device__ __forceinline__ u16 f2b(float f) {
  union { float f; unsigned u; } x;
  x.f = f;
  unsigned r = x.u + 0x7fffu + ((x.u >> 16) & 1u);
  return (u16)(r >> 16);
}

// ---------------- fp32 -> bf16 convert (all three inputs, one launch) ----------------
#define N4X 1048576   // x: 4194304 f32
#define N4W1 786432   // Wkqv: 3145728
#define N4W2 262144   // Wproj: 1048576
__global__ void cvt3_kernel(const float* __restrict__ x, const float* __restrict__ w1,
                            const float* __restrict__ w2, u16* __restrict__ ox,
                            u16* __restrict__ o1, u16* __restrict__ o2) {
  int i = blockIdx.x * blockDim.x + threadIdx.x;
  int stride = gridDim.x * blockDim.x;
  for (int idx = i; idx < N4X + N4W1 + N4W2; idx += stride) {
    const float4* src;
    ushort4* dst;
    int k;
    if (idx < N4X) { src = (const float4*)x; dst = (ushort4*)ox; k = idx; }
    else if (idx < N4X + N4W1) { src = (const float4*)w1; dst = (ushort4*)o1; k = idx - N4X; }
    else { src = (const float4*)w2; dst = (ushort4*)o2; k = idx - N4X - N4W1; }
    float4 f = src[k];
    ushort4 o;
    o.x = f2b(f.x); o.y = f2b(f.y); o.z = f2b(f.z); o.w = f2b(f.w);
    dst[k] = o;
  }
}

__device__ __forceinline__ void gload_lds16(const u16* g, u16* l) {
  __builtin_amdgcn_global_load_lds((__attribute__((address_space(1))) void*)g,
                                   (__attribute__((address_space(3))) void*)l, 16, 0, 0);
}

// ---------------- GEMM1 v17: 256x256 tile, BK=64, 8 waves, counted vmcnt ----------------
// kqv = x @ Wkqv^T + b. T3+T4 port at the geometry where it's proven to pay:
// 32 phases (16 K-tiles x 2 k-slices of 32). Each phase: vmcnt(4) [wait only the
// OLDER slice pair; newest 4 loads stay in flight across the raw s_barrier] ->
// barrier -> 12x ds_read_b128 (8 A-frags + 4 B-frags, same swizzle as the proven
// 128^2 code: each slice is a 256x32 panel) -> stage slice p of tile jt+2's...
// (jt+1) -> 32 MFMA. Slice consumed exactly one K-tile before its buffer slot is
// rewritten; per-wave vmcnt FIFOs align because every wave co-stages every slice.
// LDS: 2 bufs x (A 16K-u16 + B 16K-u16) = 128KB; C-tile (256x256 bf16 = 128KB)
// reuses it for the r14-style coalesced scatter epilogue.
__global__ __launch_bounds__(512, 2) void gemm_kqv(const u16* __restrict__ xb, const u16* __restrict__ wb,
                                                   const float* __restrict__ bias,
                                                   u16* __restrict__ qb, u16* __restrict__ kb,
                                                   u16* __restrict__ vtb) {
  __shared__ __align__(16) u16 SM[65536];  // 128KB

  const int tid = threadIdx.x;
  const int lane = tid & 63;
  const int wid = tid >> 6;        // 0..7
  const int wr = wid >> 2;         // 0..1 (M half)
  const int wc = wid & 3;          // 0..3 (N quarter)
  const int lr = lane & 15;
  const int hi = lane >> 4;
  const int frg = (hi ^ ((lr >> 1) & 3)) << 3;           // swizzled frag chunk (u16)
  const int cS = ((tid & 3) ^ ((tid >> 3) & 3)) << 3;    // pre-swizzled source col (u16)
  const int srow = tid >> 2;       // 0..127 staging row within half

  const int m0 = blockIdx.y * 256, n0 = blockIdx.x * 256;

  f32x4 acc[8][4];
#pragma unroll
  for (int i = 0; i < 8; i++)
#pragma unroll
    for (int j = 0; j < 4; j++) acc[i][j] = (f32x4){0.f, 0.f, 0.f, 0.f};

  // stage slice p (32 k) of K-tile jt into buffer b: A half-rows then B
#define STG(b, jt, p)                                                                 \
  {                                                                                   \
    const size_t ko = (size_t)(jt) * 64 + (p) * 32;                                   \
    u16* Ad = SM + (b) * 32768 + (p) * 8192;                                          \
    u16* Bd = SM + (b) * 32768 + 16384 + (p) * 8192;                                  \
    _Pragma("unroll") for (int s = 0; s < 2; s++)                                     \
      gload_lds16(&xb[(size_t)(m0 + s * 128 + srow) * CDIM + ko + cS],                \
                  &Ad[(s * 512 + tid) * 8]);                                          \
    _Pragma("unroll") for (int s = 0; s < 2; s++)                                     \
      gload_lds16(&wb[(size_t)(n0 + s * 128 + srow) * CDIM + ko + cS],                \
                  &Bd[(s * 512 + tid) * 8]);                                          \
  }

  STG(0, 0, 0)
  STG(0, 0, 1)
  for (int jt = 0; jt < 16; ++jt) {
    const int bsel = jt & 1;
#pragma unroll
    for (int p = 0; p < 2; ++p) {
      if (jt == 15 && p == 1) asm volatile("s_waitcnt vmcnt(0)" ::: "memory");
      else                    asm volatile("s_waitcnt vmcnt(4)" ::: "memory");
      __builtin_amdgcn_s_barrier();
      const u16* Ap = SM + bsel * 32768 + p * 8192;
      const u16* Bp = SM + bsel * 32768 + 16384 + p * 8192;
      Frag af[8], bf[4];
#pragma unroll
      for (int mf = 0; mf < 8; mf++)
        af[mf].i4 = *(const int4*)&Ap[(wr * 128 + mf * 16 + lr) * 32 + frg];
#pragma unroll
      for (int nf = 0; nf < 4; nf++)
        bf[nf].i4 = *(const int4*)&Bp[(wc * 64 + nf * 16 + lr) * 32 + frg];
      __builtin_amdgcn_sched_barrier(0);
      if (jt + 1 < 16) STG((jt + 1) & 1, jt + 1, p)
      __builtin_amdgcn_sched_barrier(0);
      __builtin_amdgcn_s_setprio(1);
#pragma unroll
      for (int mf = 0; mf < 8; mf++)
#pragma unroll
        for (int nf = 0; nf < 4; nf++)
          acc[mf][nf] = __builtin_amdgcn_mfma_f32_16x16x32_bf16(af[mf].b, bf[nf].b, acc[mf][nf], 0, 0, 0);
      __builtin_amdgcn_s_setprio(0);
    }
  }
#undef STG

  // ---- epilogue: C-tile to LDS (swizzled), then coalesced q/k/v^T stores ----
  __syncthreads();  // all waves done with staging LDS before C-tile overwrite
  u16* Csh = SM;    // [256][256] swizzled: elem (m,n) at n ^ (((m>>2)&3)<<4)
  const int rbase = hi << 2;
#pragma unroll
  for (int mf = 0; mf < 8; mf++) {
#pragma unroll
    for (int nf = 0; nf < 4; nf++) {
      f32x4 a = acc[mf][nf];
      int nl = wc * 64 + nf * 16 + lr;
      int n = n0 + nl;
      float bval = bias[n];
      int sres = ((n0 + wc * 64 + nf * 16) % 192) >> 6;  // uniform over the 16-run
      float scale = (sres == 1) ? 0.125f : 1.f;          // fold 1/sqrt(64) into q
#pragma unroll
      for (int r = 0; r < 4; r++) {
        int ml = wr * 128 + mf * 16 + rbase + r;
        Csh[ml * 256 + (nl ^ (((ml >> 2) & 3) << 4))] = f2b((a[r] + bval) * scale);
      }
    }
  }
  __syncthreads();

  const int bb = m0 >> 11, tt = m0 & 2047;  // 256-aligned; never crosses batch
#pragma unroll
  for (int j = 0; j < 4; j++) {
    int ns = n0 + j * 64;
    int h = ns / 192;
    int sres = (ns % 192) >> 6;
    int bh2 = (bb << 4) + h;
    if (sres == 2) {
      // v^T: dest row d holds 256 t-cols (bit2<->3 permuted per 64-group)
      int ch = tid & 31;        // 32 t-chunks x 8 = 256 t
      int d0 = tid >> 5;        // 0..15
#pragma unroll
      for (int it = 0; it < 4; it++) {
        int d = d0 + it * 16;
        unsigned pk[4];
#pragma unroll
        for (int p = 0; p < 4; p++) {
          int c0 = ch * 8 + p * 2;
          int g0 = c0 >> 6, c6a = c0 & 63;
          int mA = g0 * 64 + ((c6a & 51) | ((c6a & 8) >> 1) | ((c6a & 4) << 1));
          int c1 = c0 + 1;
          int g1 = c1 >> 6, c6b = c1 & 63;
          int mB = g1 * 64 + ((c6b & 51) | ((c6b & 8) >> 1) | ((c6b & 4) << 1));
          unsigned lo = Csh[mA * 256 + ((j * 64 + d) ^ (((mA >> 2) & 3) << 4))];
          unsigned hi2 = Csh[mB * 256 + ((j * 64 + d) ^ (((mB >> 2) & 3) << 4))];
          pk[p] = lo | (hi2 << 16);
        }
        int4 v4; v4.x = pk[0]; v4.y = pk[1]; v4.z = pk[2]; v4.w = pk[3];
        *(int4*)&vtb[((size_t)bh2 * HD + d) * TSEQ + tt + ch * 8] = v4;
      }
    } else {
      u16* dst = (sres == 0) ? kb : qb;
      int ch = tid & 7;         // 8 d-chunks x 8 = 64 d
      int rg = tid >> 3;        // 0..63
#pragma unroll
      for (int it = 0; it < 4; it++) {
        int m = rg + it * 64;
        int ccp = (j * 8 + ch) ^ (((m >> 2) & 3) << 1);  // chunk-level swizzle
        int4 v4 = *(const int4*)&Csh[m * 256 + (ccp << 3)];
        *(int4*)&dst[((size_t)bh2 * TSEQ + tt + m) * HD + ch * 8] = v4;
      }
    }
  }
}

// ---------------- GEMM2 (64x128 tile): out = y @ Wproj^T + b (fp32 out, r14-proven) ----
__device__ __forceinline__ void gemm_tiles64(const u16* __restrict__ A, const u16* __restrict__ Bw,
                                             int K, int m0, int n0,
                                             u16 (*__restrict__ Ash)[2048],
                                             u16 (*__restrict__ Bsh)[4096],
                                             f32x4 acc[2][4]) {
  const int tid = threadIdx.x;
  const int lane = tid & 63;
  const int w = tid >> 6;
  const int wr = (w >> 1) * 32, wc = (w & 1) * 64;
  const int lr = lane & 15;
  const int hi = lane >> 4;
  const int r0 = tid >> 2;                       // 0..63
  const int cS = ((tid & 3) ^ ((tid >> 3) & 3)) << 3;
  const int frg = (hi ^ ((lr >> 1) & 3)) << 3;

#define GSTAGE64(B, KO)                                                               \
  {                                                                                   \
    gload_lds16(&A[(size_t)(m0 + r0) * K + (KO) + cS], &Ash[B][tid * 8]);             \
    _Pragma("unroll") for (int s = 0; s < 2; s++)                                     \
      gload_lds16(&Bw[(size_t)(n0 + s * 64 + r0) * K + (KO) + cS], &Bsh[B][(s * 256 + tid) * 8]); \
  }

  GSTAGE64(0, 0)
  int cur = 0;
  for (int k0 = 0; k0 < K; k0 += 32) {
    __syncthreads();
    Frag af[2], bfr[4];
#pragma unroll
    for (int i = 0; i < 2; i++)
      af[i].i4 = *(const int4*)&Ash[cur][(wr + i * 16 + lr) * 32 + frg];
#pragma unroll
    for (int i = 0; i < 4; i++)
      bfr[i].i4 = *(const int4*)&Bsh[cur][(wc + i * 16 + lr) * 32 + frg];
    __builtin_amdgcn_sched_barrier(0);
    if (k0 + 32 < K) GSTAGE64(cur ^ 1, k0 + 32)
    __builtin_amdgcn_sched_barrier(0);
#pragma unroll
    for (int mf = 0; mf < 2; mf++)
#pragma unroll
      for (int nf = 0; nf < 4; nf++)
        acc[mf][nf] = __builtin_amdgcn_mfma_f32_16x16x32_bf16(af[mf].b, bfr[nf].b, acc[mf][nf], 0, 0, 0);
    cur ^= 1;
  }
#undef GSTAGE64
}

__global__ __launch_bounds__(256) void gemm_proj(const u16* __restrict__ yb, const u16* __restrict__ wb,
                                                 const float* __restrict__ bias,
                                                 float* __restrict__ out) {
  __shared__ __align__(16) u16 Ash[2][2048];
  __shared__ __align__(16) u16 Bsh[2][4096];
  const int m0 = blockIdx.y * 64, n0 = blockIdx.x * 128;
  f32x4 acc[2][4];
#pragma unroll
  for (int i = 0; i < 2; i++)
#pragma unroll
    for (int j = 0; j < 4; j++) acc[i][j] = (f32x4){0.f, 0.f, 0.f, 0.f};

  gemm_tiles64(yb, wb, CDIM, m0, n0, Ash, Bsh, acc);

  const int tid = threadIdx.x;
  const int lane = tid & 63;
  const int w = tid >> 6;
  const int wr = (w >> 1) * 32, wc = (w & 1) * 64;
  const int lr = lane & 15;
  const int rbase = (lane >> 4) << 2;
#pragma unroll
  for (int mf = 0; mf < 2; mf++) {
#pragma unroll
    for (int nf = 0; nf < 4; nf++) {
      f32x4 a = acc[mf][nf];
      int n = n0 + wc + nf * 16 + lr;
      float bval = bias[n];
#pragma unroll
      for (int r = 0; r < 4; r++) {
        int m = m0 + wr + mf * 16 + rbase + r;
        out[(size_t)m * CDIM + n] = a[r] + bval;
      }
    }
  }
}

// ---------------- causal flash attention (r16 proven: 128-wide KV tiles) ----------------
__global__ __launch_bounds__(256, 2) void attn_kernel(const u16* __restrict__ qb,
                                                      const u16* __restrict__ kb,
                                                      const u16* __restrict__ vtb,
                                                      u16* __restrict__ yb) {
  __shared__ u16 Ksh[2][128 * 64];  // [kv 128][d 64], chunk-permuted by row&7
  __shared__ u16 Vsh[2][64 * 128];  // [d 64][kv 128], per-64-group chunk-permuted

  const int tid = threadIdx.x;
  const int lane = tid & 63;
  const int w = tid >> 6;          // 0..3
  const int l31 = lane & 31;
  const int hi32 = lane >> 5;
  const int swz = l31 & 7;

  const int jj = blockIdx.x;
  const int bh = jj & 31;
  const int cls = jj >> 5;                      // 0..15
  const int qbk = (cls < 8) ? (15 - cls) : (cls - 8);  // heavy first; pair sums = 17 tiles
  const int q0w = qbk * 128 + w * 32;
  const int LN = qbk + 1;                       // 128-wide KV tiles

  const u16* Qp = qb + (size_t)bh * TSEQ * HD;
  const u16* Kp = kb + (size_t)bh * TSEQ * HD;
  const u16* Vt = vtb + (size_t)bh * HD * TSEQ;

  Frag qf[4];
#pragma unroll
  for (int k = 0; k < 4; k++)
    qf[k].i4 = *(const int4*)&Qp[(size_t)(q0w + l31) * HD + k * 16 + hi32 * 8];

  f32x16 O0, O1;
  float lp = 0.f;
#pragma unroll
  for (int i = 0; i < 16; i++) { O0[i] = 0.f; O1[i] = 0.f; }

#define STAGE(B, JT)                                                                 \
  {                                                                                  \
    const int kvb = (JT) * 128;                                                      \
    _Pragma("unroll") for (int p = 0; p < 4; p++) {                                  \
      int c = tid + p * 256;                                                         \
      int row = c >> 3, c16 = c & 7;                                                 \
      gload_lds16(&Kp[(size_t)(kvb + row) * HD + ((c16 ^ (row & 7)) << 3)],          \
                  &Ksh[B][c * 8]);                                                   \
    }                                                                                \
    _Pragma("unroll") for (int p = 0; p < 4; p++) {                                  \
      int c = tid + p * 256;                                                         \
      int row = c >> 4, c16 = c & 15;                                                \
      int gofs = ((c16 >> 3) << 6) + (((c16 & 7) ^ (row & 7)) << 3);                 \
      gload_lds16(&Vt[(size_t)row * TSEQ + kvb + gofs], &Vsh[B][c * 8]);             \
    }                                                                                \
  }

#define PACK2(dst, SV, base)                                                         \
    asm("v_cvt_pk_bf16_f32 %0, %1, %2" : "=v"(dst.i4.x) : "v"(SV[base + 0]), "v"(SV[base + 1])); \
    asm("v_cvt_pk_bf16_f32 %0, %1, %2" : "=v"(dst.i4.y) : "v"(SV[base + 2]), "v"(SV[base + 3])); \
    asm("v_cvt_pk_bf16_f32 %0, %1, %2" : "=v"(dst.i4.z) : "v"(SV[base + 4]), "v"(SV[base + 5])); \
    asm("v_cvt_pk_bf16_f32 %0, %1, %2" : "=v"(dst.i4.w) : "v"(SV[base + 6]), "v"(SV[base + 7]));

  STAGE(0, 0)
  int cur = 0;
  for (int jt = 0; jt < LN; ++jt) {
    __syncthreads();  // buf[cur] staged (prev STAGE drains here)
    const bool diag = (jt == LN - 1);
    const int wlim = diag ? w : 3;     // wave-uniform
    const u16* Kt = Ksh[cur];
    const u16* Vl = Vsh[cur];

    // ---- phase 1: ALL fragment ds_reads (before STAGE) ----
    Frag ka[4][4], vA[4][2], vB[4][2];
#pragma unroll
    for (int sh = 0; sh < 4; ++sh) {
      if (sh <= wlim) {
#pragma unroll
        for (int k = 0; k < 4; ++k)
          ka[sh][k].i4 = *(const int4*)&Kt[(sh * 32 + l31) * 64 + (((2 * k + hi32) ^ swz) << 3)];
#pragma unroll
        for (int k = 0; k < 2; ++k) {
          int cofs = ((sh >> 1) << 6) + (((((sh & 1) << 2) + 2 * k + hi32) ^ swz) << 3);
          vA[sh][k].i4 = *(const int4*)&Vl[l31 * 128 + cofs];
          vB[sh][k].i4 = *(const int4*)&Vl[(32 + l31) * 128 + cofs];
        }
      }
    }
    __builtin_amdgcn_sched_barrier(0);
    // ---- phase 2: issue next tile's staging (drains at NEXT barrier) ----
    if (jt + 1 < LN) STAGE(cur ^ 1, jt + 1)
    __builtin_amdgcn_sched_barrier(0);
    // ---- phase 3: register-only math, 4 kv-halves ----
#pragma unroll
    for (int sh = 0; sh < 4; ++sh) {
      if (sh <= wlim) {
        f32x16 S;
#pragma unroll
        for (int i = 0; i < 16; i++) S[i] = 0.f;
        __builtin_amdgcn_s_setprio(1);
#pragma unroll
        for (int k = 0; k < 4; k++)
          S = __builtin_amdgcn_mfma_f32_32x32x16_bf16(ka[sh][k].b, qf[k].b, S, 0, 0, 0);
        __builtin_amdgcn_s_setprio(0);
        if (diag && sh == w) {
#pragma unroll
          for (int reg = 0; reg < 16; reg++) {
            int crow = (reg & 3) + 8 * (reg >> 2) + 4 * hi32;
            S[reg] = (crow <= l31) ? __expf(S[reg]) : 0.f;
          }
        } else {
#pragma unroll
          for (int reg = 0; reg < 16; reg++) S[reg] = __expf(S[reg]);
        }
#pragma unroll
        for (int reg = 0; reg < 16; reg++) lp += S[reg];
        Frag pa[2];
        PACK2(pa[0], S, 0)
        PACK2(pa[1], S, 8)
        __builtin_amdgcn_s_setprio(1);
#pragma unroll
        for (int k = 0; k < 2; k++) {
          O0 = __builtin_amdgcn_mfma_f32_32x32x16_bf16(pa[k].b, vA[sh][k].b, O0, 0, 0, 0);
          O1 = __builtin_amdgcn_mfma_f32_32x32x16_bf16(pa[k].b, vB[sh][k].b, O1, 0, 0, 0);
        }
        __builtin_amdgcn_s_setprio(0);
      }
    }
    cur ^= 1;
  }
#undef STAGE
#undef PACK2

  // row sums: lane^32 partner holds the other 16 kv slots of the same q row
  float lpt = lp + __shfl_xor(lp, 32);
  const int b = bh >> 4, h = bh & 15;
#pragma unroll
  for (int reg = 0; reg < 16; reg++) {
    int qlocal = (reg & 3) + 8 * (reg >> 2) + 4 * hi32;
    float invr = 1.f / __shfl(lpt, qlocal);
    int t = q0w + qlocal;
    size_t rowoff = ((size_t)(b * TSEQ + t) << 10) + (h << 6);
    yb[rowoff + l31] = f2b(O0[reg] * invr);
    yb[rowoff + 32 + l31] = f2b(O1[reg] * invr);
  }
}

extern "C" void kernel_launch(void* const* d_in, const int* in_sizes, int n_in,
                              void* d_out, int out_size, void* d_ws, size_t ws_size,
                              hipStream_t stream) {
  const float* x = (const float*)d_in[0];
  const float* Wkqv = (const float*)d_in[1];
  const float* bkqv = (const float*)d_in[2];
  const float* Wproj = (const float*)d_in[3];
  const float* bproj = (const float*)d_in[4];
  float* out = (float*)d_out;

  u16* ws = (u16*)d_ws;
  u16* xb = ws;                       // 4194304
  u16* wkqvb = xb + 4194304;          // 3145728
  u16* wprojb = wkqvb + 3145728;      // 1048576
  u16* qb = wprojb + 1048576;         // 4194304
  u16* kb = qb + 4194304;             // 4194304
  u16* vtb = kb + 4194304;            // 4194304 ([bh][d][t], cols bit-2/3 swapped per 64)
  u16* yb = vtb + 4194304;            // 4194304  (total 48 MB)

  cvt3_kernel<<<2048, 256, 0, stream>>>(x, Wkqv, Wproj, xb, wkqvb, wprojb);
  gemm_kqv<<<dim3(12, 16), 512, 0, stream>>>(xb, wkqvb, bkqv, qb, kb, vtb);
  attn_kernel<<<512, 256, 0, stream>>>(qb, kb, vtb, yb);
  gemm_proj<<<dim3(8, 64), 256, 0, stream>>>(yb, wprojb, bproj, out);
}

// Round 18
// 89.939 us; speedup vs baseline: 1.0634x; 1.0634x over previous
//
#include <hip/hip_runtime.h>

#define TSEQ 2048
#define NHEAD 16
#define HD 64
#define CDIM 1024
#define BT 4096  // B*T

typedef unsigned short u16;
typedef __bf16 bf16x8 __attribute__((ext_vector_type(8)));
typedef float f32x4 __attribute__((ext_vector_type(4)));
typedef float f32x16 __attribute__((ext_vector_type(16)));

union Frag {
  int4 i4;
  bf16x8 b;
  u16 u[8];
};

__device__ __forceinline__ u16 f2b(float f) {
  union { float f; unsigned u; } x;
  x.f = f;
  unsigned r = x.u + 0x7fffu + ((x.u >> 16) & 1u);
  return (u16)(r >> 16);
}

// ---------------- fp32 -> bf16 convert (all three inputs, one launch) ----------------
#define N4X 1048576   // x: 4194304 f32
#define N4W1 786432   // Wkqv: 3145728
#define N4W2 262144   // Wproj: 1048576
__global__ void cvt3_kernel(const float* __restrict__ x, const float* __restrict__ w1,
                            const float* __restrict__ w2, u16* __restrict__ ox,
                            u16* __restrict__ o1, u16* __restrict__ o2) {
  int i = blockIdx.x * blockDim.x + threadIdx.x;
  int stride = gridDim.x * blockDim.x;
  for (int idx = i; idx < N4X + N4W1 + N4W2; idx += stride) {
    const float4* src;
    ushort4* dst;
    int k;
    if (idx < N4X) { src = (const float4*)x; dst = (ushort4*)ox; k = idx; }
    else if (idx < N4X + N4W1) { src = (const float4*)w1; dst = (ushort4*)o1; k = idx - N4X; }
    else { src = (const float4*)w2; dst = (ushort4*)o2; k = idx - N4X - N4W1; }
    float4 f = src[k];
    ushort4 o;
    o.x = f2b(f.x); o.y = f2b(f.y); o.z = f2b(f.z); o.w = f2b(f.w);
    dst[k] = o;
  }
}

__device__ __forceinline__ void gload_lds16(const u16* g, u16* l) {
  __builtin_amdgcn_global_load_lds((__attribute__((address_space(1))) void*)g,
                                   (__attribute__((address_space(3))) void*)l, 16, 0, 0);
}

// ---------------- GEMM1 v18: 128x384 tile, BK=64, 8 waves, counted vmcnt ----------------
// kqv = x @ Wkqv^T + b. r17's verified slice-phase protocol (vmcnt(4), raw barrier,
// read->stage->MFMA) at a grid-exact tile: 8x32 = 256 blocks = exactly 1/CU (r17's
// 256^2 tied r16 while leaving 25% of CUs idle -> per-CU rate is the win; this
// recovers the idle CUs). Per slice-phase: A 1 load + B 3 loads per thread
// (uniform), 4 A-frags + 6 B-frags ds_read, 24 MFMA/wave. LDS 128KB staging;
// C-tile (128x384 = 96KB) reuses it. n0 = 384*bx spans exactly 2 heads: the six
// 64-groups map 1:1 to k/q/v slabs of heads 2bx, 2bx+1.
__global__ __launch_bounds__(512, 2) void gemm_kqv(const u16* __restrict__ xb, const u16* __restrict__ wb,
                                                   const float* __restrict__ bias,
                                                   u16* __restrict__ qb, u16* __restrict__ kb,
                                                   u16* __restrict__ vtb) {
  __shared__ __align__(16) u16 SM[65536];  // 128KB

  const int tid = threadIdx.x;
  const int lane = tid & 63;
  const int wid = tid >> 6;        // 0..7
  const int wr = wid >> 2;         // 0..1 (M half of 64)
  const int wc = wid & 3;          // 0..3 (N quarter of 96)
  const int lr = lane & 15;
  const int hi = lane >> 4;
  const int frg = (hi ^ ((lr >> 1) & 3)) << 3;   // swizzled frag chunk (u16)

  const int m0 = blockIdx.y * 128, n0 = blockIdx.x * 384;

  f32x4 acc[4][6];
#pragma unroll
  for (int i = 0; i < 4; i++)
#pragma unroll
    for (int j = 0; j < 6; j++) acc[i][j] = (f32x4){0.f, 0.f, 0.f, 0.f};

  // stage slice p (32 k) of K-tile jt into buffer b. A: 512 chunks (1/thr),
  // B: 1536 chunks (3/thr). Source col pre-swizzled: chunk c16 ^ ((row>>1)&3).
#define STG(b, jt, p)                                                                 \
  {                                                                                   \
    const size_t ko = (size_t)(jt) * 64 + (p) * 32;                                   \
    u16* Ad = SM + (b) * 32768 + (p) * 4096;                                          \
    u16* Bd = SM + (b) * 32768 + 8192 + (p) * 12288;                                  \
    { int c = tid; int row = c >> 2, c16 = c & 3;                                     \
      gload_lds16(&xb[(size_t)(m0 + row) * CDIM + ko + ((c16 ^ ((row >> 1) & 3)) << 3)], \
                  &Ad[c * 8]); }                                                      \
    _Pragma("unroll") for (int s = 0; s < 3; s++) {                                   \
      int c = tid + s * 512; int row = c >> 2, c16 = c & 3;                           \
      gload_lds16(&wb[(size_t)(n0 + row) * CDIM + ko + ((c16 ^ ((row >> 1) & 3)) << 3)], \
                  &Bd[c * 8]); }                                                      \
  }

  STG(0, 0, 0)
  STG(0, 0, 1)
  for (int jt = 0; jt < 16; ++jt) {
    const int bsel = jt & 1;
#pragma unroll
    for (int p = 0; p < 2; ++p) {
      if (jt == 15 && p == 1) asm volatile("s_waitcnt vmcnt(0)" ::: "memory");
      else                    asm volatile("s_waitcnt vmcnt(4)" ::: "memory");
      __builtin_amdgcn_s_barrier();
      const u16* Ap = SM + bsel * 32768 + p * 4096;
      const u16* Bp = SM + bsel * 32768 + 8192 + p * 12288;
      Frag af[4], bf[6];
#pragma unroll
      for (int mf = 0; mf < 4; mf++)
        af[mf].i4 = *(const int4*)&Ap[(wr * 64 + mf * 16 + lr) * 32 + frg];
#pragma unroll
      for (int nf = 0; nf < 6; nf++)
        bf[nf].i4 = *(const int4*)&Bp[(wc * 96 + nf * 16 + lr) * 32 + frg];
      __builtin_amdgcn_sched_barrier(0);
      if (jt + 1 < 16) STG((jt + 1) & 1, jt + 1, p)
      __builtin_amdgcn_sched_barrier(0);
      __builtin_amdgcn_s_setprio(1);
#pragma unroll
      for (int mf = 0; mf < 4; mf++)
#pragma unroll
        for (int nf = 0; nf < 6; nf++)
          acc[mf][nf] = __builtin_amdgcn_mfma_f32_16x16x32_bf16(af[mf].b, bf[nf].b, acc[mf][nf], 0, 0, 0);
      __builtin_amdgcn_s_setprio(0);
    }
  }
#undef STG

  // ---- epilogue: C-tile to LDS (swizzled), then coalesced q/k/v^T stores ----
  __syncthreads();  // all waves done with staging LDS before C-tile overwrite
  u16* Csh = SM;    // [128][384] swizzled: elem (m,n) at n ^ (((m>>2)&3)<<4)
  const int rbase = hi << 2;
#pragma unroll
  for (int mf = 0; mf < 4; mf++) {
#pragma unroll
    for (int nf = 0; nf < 6; nf++) {
      f32x4 a = acc[mf][nf];
      int nl = wc * 96 + nf * 16 + lr;
      int n = n0 + nl;
      float bval = bias[n];
      int sres = ((wc * 96 + nf * 16) % 192) >> 6;   // n0 % 192 == 0; uniform per 16-run
      float scale = (sres == 1) ? 0.125f : 1.f;      // fold 1/sqrt(64) into q
#pragma unroll
      for (int r = 0; r < 4; r++) {
        int ml = wr * 64 + mf * 16 + rbase + r;
        Csh[ml * 384 + (nl ^ (((ml >> 2) & 3) << 4))] = f2b((a[r] + bval) * scale);
      }
    }
  }
  __syncthreads();

  const int bb = m0 >> 11, tt = m0 & 2047;  // 128-aligned
#pragma unroll
  for (int j = 0; j < 6; j++) {
    int sres = j % 3;                 // group -> k/q/v
    int h = 2 * blockIdx.x + j / 3;   // exactly two heads per block
    int bh2 = (bb << 4) + h;
    if (sres == 2) {
      // v^T: dest row d holds 128 t-cols (bit2<->3 permuted per 64-group)
      int ch = tid & 15;        // 16 t-chunks x 8 = 128 t
      int d0 = tid >> 4;        // 0..31
#pragma unroll
      for (int it = 0; it < 2; it++) {
        int d = d0 + it * 32;
        unsigned pk[4];
#pragma unroll
        for (int p = 0; p < 4; p++) {
          int c0 = ch * 8 + p * 2;
          int g0 = c0 >> 6, c6a = c0 & 63;
          int mA = g0 * 64 + ((c6a & 51) | ((c6a & 8) >> 1) | ((c6a & 4) << 1));
          int c1 = c0 + 1;
          int g1 = c1 >> 6, c6b = c1 & 63;
          int mB = g1 * 64 + ((c6b & 51) | ((c6b & 8) >> 1) | ((c6b & 4) << 1));
          unsigned lo = Csh[mA * 384 + ((j * 64 + d) ^ (((mA >> 2) & 3) << 4))];
          unsigned hi2 = Csh[mB * 384 + ((j * 64 + d) ^ (((mB >> 2) & 3) << 4))];
          pk[p] = lo | (hi2 << 16);
        }
        int4 v4; v4.x = pk[0]; v4.y = pk[1]; v4.z = pk[2]; v4.w = pk[3];
        *(int4*)&vtb[((size_t)bh2 * HD + d) * TSEQ + tt + ch * 8] = v4;
      }
    } else {
      u16* dst = (sres == 0) ? kb : qb;
      int ch = tid & 7;         // 8 d-chunks x 8 = 64 d
      int rg = tid >> 3;        // 0..63
#pragma unroll
      for (int it = 0; it < 2; it++) {
        int m = rg + it * 64;
        int ccp = (j * 8 + ch) ^ (((m >> 2) & 3) << 1);  // chunk-level swizzle
        int4 v4 = *(const int4*)&Csh[m * 384 + (ccp << 3)];
        *(int4*)&dst[((size_t)bh2 * TSEQ + tt + m) * HD + ch * 8] = v4;
      }
    }
  }
}

// ---------------- GEMM2 (64x128 tile): out = y @ Wproj^T + b (fp32 out, r14-proven) ----
__device__ __forceinline__ void gemm_tiles64(const u16* __restrict__ A, const u16* __restrict__ Bw,
                                             int K, int m0, int n0,
                                             u16 (*__restrict__ Ash)[2048],
                                             u16 (*__restrict__ Bsh)[4096],
                                             f32x4 acc[2][4]) {
  const int tid = threadIdx.x;
  const int lane = tid & 63;
  const int w = tid >> 6;
  const int wr = (w >> 1) * 32, wc = (w & 1) * 64;
  const int lr = lane & 15;
  const int hi = lane >> 4;
  const int r0 = tid >> 2;                       // 0..63
  const int cS = ((tid & 3) ^ ((tid >> 3) & 3)) << 3;
  const int frg = (hi ^ ((lr >> 1) & 3)) << 3;

#define GSTAGE64(B, KO)                                                               \
  {                                                                                   \
    gload_lds16(&A[(size_t)(m0 + r0) * K + (KO) + cS], &Ash[B][tid * 8]);             \
    _Pragma("unroll") for (int s = 0; s < 2; s++)                                     \
      gload_lds16(&Bw[(size_t)(n0 + s * 64 + r0) * K + (KO) + cS], &Bsh[B][(s * 256 + tid) * 8]); \
  }

  GSTAGE64(0, 0)
  int cur = 0;
  for (int k0 = 0; k0 < K; k0 += 32) {
    __syncthreads();
    Frag af[2], bfr[4];
#pragma unroll
    for (int i = 0; i < 2; i++)
      af[i].i4 = *(const int4*)&Ash[cur][(wr + i * 16 + lr) * 32 + frg];
#pragma unroll
    for (int i = 0; i < 4; i++)
      bfr[i].i4 = *(const int4*)&Bsh[cur][(wc + i * 16 + lr) * 32 + frg];
    __builtin_amdgcn_sched_barrier(0);
    if (k0 + 32 < K) GSTAGE64(cur ^ 1, k0 + 32)
    __builtin_amdgcn_sched_barrier(0);
#pragma unroll
    for (int mf = 0; mf < 2; mf++)
#pragma unroll
      for (int nf = 0; nf < 4; nf++)
        acc[mf][nf] = __builtin_amdgcn_mfma_f32_16x16x32_bf16(af[mf].b, bfr[nf].b, acc[mf][nf], 0, 0, 0);
    cur ^= 1;
  }
#undef GSTAGE64
}

__global__ __launch_bounds__(256) void gemm_proj(const u16* __restrict__ yb, const u16* __restrict__ wb,
                                                 const float* __restrict__ bias,
                                                 float* __restrict__ out) {
  __shared__ __align__(16) u16 Ash[2][2048];
  __shared__ __align__(16) u16 Bsh[2][4096];
  const int m0 = blockIdx.y * 64, n0 = blockIdx.x * 128;
  f32x4 acc[2][4];
#pragma unroll
  for (int i = 0; i < 2; i++)
#pragma unroll
    for (int j = 0; j < 4; j++) acc[i][j] = (f32x4){0.f, 0.f, 0.f, 0.f};

  gemm_tiles64(yb, wb, CDIM, m0, n0, Ash, Bsh, acc);

  const int tid = threadIdx.x;
  const int lane = tid & 63;
  const int w = tid >> 6;
  const int wr = (w >> 1) * 32, wc = (w & 1) * 64;
  const int lr = lane & 15;
  const int rbase = (lane >> 4) << 2;
#pragma unroll
  for (int mf = 0; mf < 2; mf++) {
#pragma unroll
    for (int nf = 0; nf < 4; nf++) {
      f32x4 a = acc[mf][nf];
      int n = n0 + wc + nf * 16 + lr;
      float bval = bias[n];
#pragma unroll
      for (int r = 0; r < 4; r++) {
        int m = m0 + wr + mf * 16 + rbase + r;
        out[(size_t)m * CDIM + n] = a[r] + bval;
      }
    }
  }
}

// ---------------- causal flash attention (r16 proven: 128-wide KV tiles) ----------------
__global__ __launch_bounds__(256, 2) void attn_kernel(const u16* __restrict__ qb,
                                                      const u16* __restrict__ kb,
                                                      const u16* __restrict__ vtb,
                                                      u16* __restrict__ yb) {
  __shared__ u16 Ksh[2][128 * 64];  // [kv 128][d 64], chunk-permuted by row&7
  __shared__ u16 Vsh[2][64 * 128];  // [d 64][kv 128], per-64-group chunk-permuted

  const int tid = threadIdx.x;
  const int lane = tid & 63;
  const int w = tid >> 6;          // 0..3
  const int l31 = lane & 31;
  const int hi32 = lane >> 5;
  const int swz = l31 & 7;

  const int jj = blockIdx.x;
  const int bh = jj & 31;
  const int cls = jj >> 5;                      // 0..15
  const int qbk = (cls < 8) ? (15 - cls) : (cls - 8);  // heavy first; pair sums = 17 tiles
  const int q0w = qbk * 128 + w * 32;
  const int LN = qbk + 1;                       // 128-wide KV tiles

  const u16* Qp = qb + (size_t)bh * TSEQ * HD;
  const u16* Kp = kb + (size_t)bh * TSEQ * HD;
  const u16* Vt = vtb + (size_t)bh * HD * TSEQ;

  Frag qf[4];
#pragma unroll
  for (int k = 0; k < 4; k++)
    qf[k].i4 = *(const int4*)&Qp[(size_t)(q0w + l31) * HD + k * 16 + hi32 * 8];

  f32x16 O0, O1;
  float lp = 0.f;
#pragma unroll
  for (int i = 0; i < 16; i++) { O0[i] = 0.f; O1[i] = 0.f; }

#define STAGE(B, JT)                                                                 \
  {                                                                                  \
    const int kvb = (JT) * 128;                                                      \
    _Pragma("unroll") for (int p = 0; p < 4; p++) {                                  \
      int c = tid + p * 256;                                                         \
      int row = c >> 3, c16 = c & 7;                                                 \
      gload_lds16(&Kp[(size_t)(kvb + row) * HD + ((c16 ^ (row & 7)) << 3)],          \
                  &Ksh[B][c * 8]);                                                   \
    }                                                                                \
    _Pragma("unroll") for (int p = 0; p < 4; p++) {                                  \
      int c = tid + p * 256;                                                         \
      int row = c >> 4, c16 = c & 15;                                                \
      int gofs = ((c16 >> 3) << 6) + (((c16 & 7) ^ (row & 7)) << 3);                 \
      gload_lds16(&Vt[(size_t)row * TSEQ + kvb + gofs], &Vsh[B][c * 8]);             \
    }                                                                                \
  }

#define PACK2(dst, SV, base)                                                         \
    asm("v_cvt_pk_bf16_f32 %0, %1, %2" : "=v"(dst.i4.x) : "v"(SV[base + 0]), "v"(SV[base + 1])); \
    asm("v_cvt_pk_bf16_f32 %0, %1, %2" : "=v"(dst.i4.y) : "v"(SV[base + 2]), "v"(SV[base + 3])); \
    asm("v_cvt_pk_bf16_f32 %0, %1, %2" : "=v"(dst.i4.z) : "v"(SV[base + 4]), "v"(SV[base + 5])); \
    asm("v_cvt_pk_bf16_f32 %0, %1, %2" : "=v"(dst.i4.w) : "v"(SV[base + 6]), "v"(SV[base + 7]));

  STAGE(0, 0)
  int cur = 0;
  for (int jt = 0; jt < LN; ++jt) {
    __syncthreads();  // buf[cur] staged (prev STAGE drains here)
    const bool diag = (jt == LN - 1);
    const int wlim = diag ? w : 3;     // wave-uniform
    const u16* Kt = Ksh[cur];
    const u16* Vl = Vsh[cur];

    // ---- phase 1: ALL fragment ds_reads (before STAGE) ----
    Frag ka[4][4], vA[4][2], vB[4][2];
#pragma unroll
    for (int sh = 0; sh < 4; ++sh) {
      if (sh <= wlim) {
#pragma unroll
        for (int k = 0; k < 4; ++k)
          ka[sh][k].i4 = *(const int4*)&Kt[(sh * 32 + l31) * 64 + (((2 * k + hi32) ^ swz) << 3)];
#pragma unroll
        for (int k = 0; k < 2; ++k) {
          int cofs = ((sh >> 1) << 6) + (((((sh & 1) << 2) + 2 * k + hi32) ^ swz) << 3);
          vA[sh][k].i4 = *(const int4*)&Vl[l31 * 128 + cofs];
          vB[sh][k].i4 = *(const int4*)&Vl[(32 + l31) * 128 + cofs];
        }
      }
    }
    __builtin_amdgcn_sched_barrier(0);
    // ---- phase 2: issue next tile's staging (drains at NEXT barrier) ----
    if (jt + 1 < LN) STAGE(cur ^ 1, jt + 1)
    __builtin_amdgcn_sched_barrier(0);
    // ---- phase 3: register-only math, 4 kv-halves ----
#pragma unroll
    for (int sh = 0; sh < 4; ++sh) {
      if (sh <= wlim) {
        f32x16 S;
#pragma unroll
        for (int i = 0; i < 16; i++) S[i] = 0.f;
        __builtin_amdgcn_s_setprio(1);
#pragma unroll
        for (int k = 0; k < 4; k++)
          S = __builtin_amdgcn_mfma_f32_32x32x16_bf16(ka[sh][k].b, qf[k].b, S, 0, 0, 0);
        __builtin_amdgcn_s_setprio(0);
        if (diag && sh == w) {
#pragma unroll
          for (int reg = 0; reg < 16; reg++) {
            int crow = (reg & 3) + 8 * (reg >> 2) + 4 * hi32;
            S[reg] = (crow <= l31) ? __expf(S[reg]) : 0.f;
          }
        } else {
#pragma unroll
          for (int reg = 0; reg < 16; reg++) S[reg] = __expf(S[reg]);
        }
#pragma unroll
        for (int reg = 0; reg < 16; reg++) lp += S[reg];
        Frag pa[2];
        PACK2(pa[0], S, 0)
        PACK2(pa[1], S, 8)
        __builtin_amdgcn_s_setprio(1);
#pragma unroll
        for (int k = 0; k < 2; k++) {
          O0 = __builtin_amdgcn_mfma_f32_32x32x16_bf16(pa[k].b, vA[sh][k].b, O0, 0, 0, 0);
          O1 = __builtin_amdgcn_mfma_f32_32x32x16_bf16(pa[k].b, vB[sh][k].b, O1, 0, 0, 0);
        }
        __builtin_amdgcn_s_setprio(0);
      }
    }
    cur ^= 1;
  }
#undef STAGE
#undef PACK2

  // row sums: lane^32 partner holds the other 16 kv slots of the same q row
  float lpt = lp + __shfl_xor(lp, 32);
  const int b = bh >> 4, h = bh & 15;
#pragma unroll
  for (int reg = 0; reg < 16; reg++) {
    int qlocal = (reg & 3) + 8 * (reg >> 2) + 4 * hi32;
    float invr = 1.f / __shfl(lpt, qlocal);
    int t = q0w + qlocal;
    size_t rowoff = ((size_t)(b * TSEQ + t) << 10) + (h << 6);
    yb[rowoff + l31] = f2b(O0[reg] * invr);
    yb[rowoff + 32 + l31] = f2b(O1[reg] * invr);
  }
}

extern "C" void kernel_launch(void* const* d_in, const int* in_sizes, int n_in,
                              void* d_out, int out_size, void* d_ws, size_t ws_size,
                              hipStream_t stream) {
  const float* x = (const float*)d_in[0];
  const float* Wkqv = (const float*)d_in[1];
  const float* bkqv = (const float*)d_in[2];
  const float* Wproj = (const float*)d_in[3];
  const float* bproj = (const float*)d_in[4];
  float* out = (float*)d_out;

  u16* ws = (u16*)d_ws;
  u16* xb = ws;                       // 4194304
  u16* wkqvb = xb + 4194304;          // 3145728
  u16* wprojb = wkqvb + 3145728;      // 1048576
  u16* qb = wprojb + 1048576;         // 4194304
  u16* kb = qb + 4194304;             // 4194304
  u16* vtb = kb + 4194304;            // 4194304 ([bh][d][t], cols bit-2/3 swapped per 64)
  u16* yb = vtb + 4194304;            // 4194304  (total 48 MB)

  cvt3_kernel<<<2048, 256, 0, stream>>>(x, Wkqv, Wproj, xb, wkqvb, wprojb);
  gemm_kqv<<<dim3(8, 32), 512, 0, stream>>>(xb, wkqvb, bkqv, qb, kb, vtb);
  attn_kernel<<<512, 256, 0, stream>>>(qb, kb, vtb, yb);
  gemm_proj<<<dim3(8, 64), 256, 0, stream>>>(yb, wprojb, bproj, out);
}